// Round 1
// baseline (790.285 us; speedup 1.0000x reference)
//
#include <hip/hip_runtime.h>
#include <hip/hip_bf16.h>

#define NEG_SLOPE 0.2f
#define BN_EPS 1e-5f

// ---------- helpers ----------
__device__ __forceinline__ unsigned ford(float f) {
    unsigned u = __float_as_uint(f);
    return (u & 0x80000000u) ? ~u : (u | 0x80000000u);
}
__device__ __forceinline__ float fordinv(unsigned u) {
    return __uint_as_float((u & 0x80000000u) ? (u ^ 0x80000000u) : ~u);
}
__device__ __forceinline__ float lrelu(float x) { return x > 0.f ? x : NEG_SLOPE * x; }

// ---------- kernel A: h = x @ W^T, a_src/a_dst, init segmax/segsum/acc ----------
// block = 256 threads, each block handles 64 nodes. LDS-tiled, padded (+1) strides.
__global__ void k_gemm_h(const float* __restrict__ x, const float* __restrict__ W,
                         const float* __restrict__ att_src, const float* __restrict__ att_dst,
                         float* __restrict__ h, float* __restrict__ aS, float* __restrict__ aD,
                         unsigned* __restrict__ smax, float* __restrict__ ssum,
                         float* __restrict__ acc, int N)
{
    __shared__ float Wt[64][65];   // Wt[k][cout] = W[cout][k]
    __shared__ float xs[64][65];   // xs[nl][k]
    const int t = threadIdx.x;
    const int n0 = blockIdx.x * 64;

    #pragma unroll
    for (int i = 0; i < 16; ++i) {
        int idx = i * 256 + t;
        int r = idx >> 6, c = idx & 63;   // r = cout, c = k
        Wt[c][r] = W[idx];
    }
    #pragma unroll
    for (int i = 0; i < 16; ++i) {
        int idx = i * 256 + t;
        int nl = idx >> 6, k = idx & 63;
        int n = n0 + nl;
        xs[nl][k] = (n < N) ? x[(size_t)n * 64 + k] : 0.f;
    }
    __syncthreads();

    const int c = t & 63;        // output channel (lane)
    const int nl0 = t >> 6;      // wave id in block
    const float asc = att_src[c];
    const float adc = att_dst[c];

    for (int nl = nl0; nl < 64; nl += 4) {
        int n = n0 + nl;
        if (n >= N) break;
        float a = 0.f;
        #pragma unroll
        for (int k = 0; k < 64; ++k) a = fmaf(xs[nl][k], Wt[k][c], a);
        h[(size_t)n * 64 + c]   = a;
        acc[(size_t)n * 64 + c] = 0.f;
        // wave-reduce a*att over 64 lanes
        float s = a * asc, d = a * adc;
        #pragma unroll
        for (int off = 32; off; off >>= 1) { s += __shfl_xor(s, off); d += __shfl_xor(d, off); }
        if (c == 0) {
            aS[n] = s; aD[n] = d;
            float ls = lrelu(s + d);      // self-loop logit
            smax[n] = ford(ls);           // init segment max with self-loop
            ssum[n] = 0.f;
        }
    }
}

// ---------- kernel B: per-edge logit + atomicMax into segmax[dst] ----------
__global__ void k_edge_logits(const int* __restrict__ ei, const float* __restrict__ aS,
                              const float* __restrict__ aD, float* __restrict__ logits,
                              unsigned* __restrict__ smax, int E)
{
    int e = blockIdx.x * 256 + threadIdx.x;
    if (e >= E) return;
    int s = ei[e];
    int d = ei[E + e];
    float l = lrelu(aS[s] + aD[d]);
    logits[e] = l;
    atomicMax(&smax[d], ford(l));
}

// ---------- kernel C: unnormalized weighted scatter: acc[dst] += w*h[src]; ssum[dst] += w ----------
// one wave per edge (64 lanes = 64 channels)
__global__ void k_edge_accum(const int* __restrict__ ei, const float* __restrict__ logits,
                             const unsigned* __restrict__ smax, const float* __restrict__ h,
                             float* __restrict__ acc, float* __restrict__ ssum, int E)
{
    int gid = blockIdx.x * 256 + threadIdx.x;
    int e = gid >> 6;
    if (e >= E) return;
    int c = gid & 63;
    int s = ei[e];
    int d = ei[E + e];
    float m = fordinv(smax[d]);
    float w = __expf(logits[e] - m);
    unsafeAtomicAdd(&acc[(size_t)d * 64 + c], w * h[(size_t)s * 64 + c]);
    if (c == 0) unsafeAtomicAdd(&ssum[d], w);
}

// ---------- kernel D: finalize GAT (self-loop + normalize + conv_b), BN partial sums ----------
// grid-stride; thread = (node, channel); register partials -> LDS -> global atomics
__global__ void k_finalize_bn(const float* __restrict__ h, const float* __restrict__ aS,
                              const float* __restrict__ aD, const unsigned* __restrict__ smax,
                              const float* __restrict__ ssum, const float* __restrict__ conv_b,
                              float* __restrict__ acc, float* __restrict__ bnsum,
                              float* __restrict__ bnsq, int N)
{
    const int t = threadIdx.x;
    const int c = t & 63;
    const float bc = conv_b[c];
    float psum = 0.f, psq = 0.f;
    const int stride = (gridDim.x * blockDim.x) >> 6;
    for (int n = (blockIdx.x * blockDim.x + t) >> 6; n < N; n += stride) {
        float ls = lrelu(aS[n] + aD[n]);
        float m  = fordinv(smax[n]);
        float es = __expf(ls - m);                 // self-loop weight
        float inv = 1.f / (ssum[n] + es);
        size_t off = (size_t)n * 64 + c;
        float v = fmaf(es, h[off], acc[off]) * inv + bc;
        acc[off] = v;                              // in-place: acc becomes h_gat
        psum += v;
        psq  = fmaf(v, v, psq);
    }
    __shared__ float ps[4][64], pq[4][64];
    ps[t >> 6][c] = psum;
    pq[t >> 6][c] = psq;
    __syncthreads();
    if (t < 64) {
        float s = ps[0][t] + ps[1][t] + ps[2][t] + ps[3][t];
        float q = pq[0][t] + pq[1][t] + pq[2][t] + pq[3][t];
        unsafeAtomicAdd(&bnsum[t], s);
        unsafeAtomicAdd(&bnsq[t],  q);
    }
}

// ---------- kernel E: BN scale/shift ----------
__global__ void k_bn_params(const float* __restrict__ bnsum, const float* __restrict__ bnsq,
                            const float* __restrict__ gamma, const float* __restrict__ beta,
                            float* __restrict__ scale, float* __restrict__ shift, int N)
{
    int c = threadIdx.x;
    float invN = 1.f / (float)N;
    float mu  = bnsum[c] * invN;
    float var = bnsq[c] * invN - mu * mu;
    float sc  = gamma[c] * rsqrtf(var + BN_EPS);
    scale[c] = sc;
    shift[c] = beta[c] - mu * sc;
}

// ---------- kernel F: BN apply + ReLU + FC(64->32) ----------
__global__ void k_bn_fc(const float* __restrict__ hg, const float* __restrict__ scale,
                        const float* __restrict__ shift, const float* __restrict__ fcW,
                        const float* __restrict__ fcb, float* __restrict__ out, int N)
{
    __shared__ float Ws[2048];
    __shared__ float sc[64], sh[64];
    const int t = threadIdx.x;
    for (int i = t; i < 2048; i += 256) Ws[i] = fcW[i];
    if (t < 64) { sc[t] = scale[t]; sh[t] = shift[t]; }
    __syncthreads();
    int n = blockIdx.x * 256 + t;
    if (n >= N) return;
    float y[64];
    const float4* hp = (const float4*)(hg + (size_t)n * 64);
    #pragma unroll
    for (int i = 0; i < 16; ++i) {
        float4 v = hp[i];
        y[4*i+0] = fmaxf(fmaf(v.x, sc[4*i+0], sh[4*i+0]), 0.f);
        y[4*i+1] = fmaxf(fmaf(v.y, sc[4*i+1], sh[4*i+1]), 0.f);
        y[4*i+2] = fmaxf(fmaf(v.z, sc[4*i+2], sh[4*i+2]), 0.f);
        y[4*i+3] = fmaxf(fmaf(v.w, sc[4*i+3], sh[4*i+3]), 0.f);
    }
    float4* op = (float4*)(out + (size_t)n * 32);
    #pragma unroll
    for (int o4 = 0; o4 < 8; ++o4) {
        float a0 = fcb[4*o4+0], a1 = fcb[4*o4+1], a2 = fcb[4*o4+2], a3 = fcb[4*o4+3];
        #pragma unroll
        for (int k = 0; k < 64; ++k) {
            float yv = y[k];
            a0 = fmaf(yv, Ws[(4*o4+0)*64+k], a0);
            a1 = fmaf(yv, Ws[(4*o4+1)*64+k], a1);
            a2 = fmaf(yv, Ws[(4*o4+2)*64+k], a2);
            a3 = fmaf(yv, Ws[(4*o4+3)*64+k], a3);
        }
        op[o4] = make_float4(a0, a1, a2, a3);
    }
}

// ---------- launch ----------
extern "C" void kernel_launch(void* const* d_in, const int* in_sizes, int n_in,
                              void* d_out, int out_size, void* d_ws, size_t ws_size,
                              hipStream_t stream)
{
    const float* x       = (const float*)d_in[0];
    const int*   ei      = (const int*)d_in[1];
    const float* W       = (const float*)d_in[2];
    const float* att_src = (const float*)d_in[3];
    const float* att_dst = (const float*)d_in[4];
    const float* conv_b  = (const float*)d_in[5];
    const float* gamma   = (const float*)d_in[6];
    const float* beta    = (const float*)d_in[7];
    const float* fcW     = (const float*)d_in[8];
    const float* fcb     = (const float*)d_in[9];

    const int N = in_sizes[0] / 64;
    const int E = in_sizes[1] / 2;

    // workspace layout (floats)
    float* ws = (float*)d_ws;
    size_t N64 = (size_t)N * 64;
    float*    h      = ws;                       // N*64
    float*    acc    = h + N64;                  // N*64  (becomes h_gat in-place)
    float*    aS     = acc + N64;                // N
    float*    aD     = aS + N;                   // N
    unsigned* smax   = (unsigned*)(aD + N);      // N
    float*    ssum   = (float*)(smax + N);       // N
    float*    logits = ssum + N;                 // E
    float*    bnsum  = logits + E;               // 64
    float*    bnsq   = bnsum + 64;               // 64
    float*    scale  = bnsq + 64;                // 64
    float*    shift  = scale + 64;               // 64

    hipMemsetAsync(bnsum, 0, 2 * 64 * sizeof(float), stream);

    k_gemm_h<<<(N + 63) / 64, 256, 0, stream>>>(x, W, att_src, att_dst,
                                                h, aS, aD, smax, ssum, acc, N);
    k_edge_logits<<<(E + 255) / 256, 256, 0, stream>>>(ei, aS, aD, logits, smax, E);

    int cThreads = E * 64;  // 102.4M, fits int
    k_edge_accum<<<(cThreads + 255) / 256, 256, 0, stream>>>(ei, logits, smax, h, acc, ssum, E);

    k_finalize_bn<<<2048, 256, 0, stream>>>(h, aS, aD, smax, ssum, conv_b,
                                            acc, bnsum, bnsq, N);
    k_bn_params<<<1, 64, 0, stream>>>(bnsum, bnsq, gamma, beta, scale, shift, N);
    k_bn_fc<<<(N + 255) / 256, 256, 0, stream>>>(acc, scale, shift, fcW, fcb,
                                                 (float*)d_out, N);
}

// Round 2
// 592.294 us; speedup vs baseline: 1.3343x; 1.3343x over previous
//
#include <hip/hip_runtime.h>
#include <hip/hip_bf16.h>

#define NEG_SLOPE 0.2f
#define BN_EPS 1e-5f
#define SCAN_CHUNK 4096

__device__ __forceinline__ float lrelu(float x) { return x > 0.f ? x : NEG_SLOPE * x; }

// ---------- kernel A: h = x @ W^T, a_src/a_dst ----------
__global__ void k_gemm_h(const float* __restrict__ x, const float* __restrict__ W,
                         const float* __restrict__ att_src, const float* __restrict__ att_dst,
                         float* __restrict__ h, float* __restrict__ aS, float* __restrict__ aD,
                         int N)
{
    __shared__ float Wt[64][65];   // Wt[k][cout] = W[cout][k]
    __shared__ float xs[64][65];   // xs[nl][k]
    const int t = threadIdx.x;
    const int n0 = blockIdx.x * 64;

    #pragma unroll
    for (int i = 0; i < 16; ++i) {
        int idx = i * 256 + t;
        int r = idx >> 6, c = idx & 63;   // r = cout, c = k
        Wt[c][r] = W[idx];
    }
    #pragma unroll
    for (int i = 0; i < 16; ++i) {
        int idx = i * 256 + t;
        int nl = idx >> 6, k = idx & 63;
        int n = n0 + nl;
        xs[nl][k] = (n < N) ? x[(size_t)n * 64 + k] : 0.f;
    }
    __syncthreads();

    const int c = t & 63;
    const int nl0 = t >> 6;
    const float asc = att_src[c];
    const float adc = att_dst[c];

    for (int nl = nl0; nl < 64; nl += 4) {
        int n = n0 + nl;
        if (n >= N) break;
        float a = 0.f;
        #pragma unroll
        for (int k = 0; k < 64; ++k) a = fmaf(xs[nl][k], Wt[k][c], a);
        h[(size_t)n * 64 + c] = a;
        float s = a * asc, d = a * adc;
        #pragma unroll
        for (int off = 32; off; off >>= 1) { s += __shfl_xor(s, off); d += __shfl_xor(d, off); }
        if (c == 0) { aS[n] = s; aD[n] = d; }
    }
}

// ---------- CSR build ----------
__global__ void k_hist(const int* __restrict__ ei, int* __restrict__ deg, int E) {
    int e = blockIdx.x * 256 + threadIdx.x;
    if (e < E) atomicAdd(&deg[ei[E + e]], 1);
}

__global__ void k_scan1(const int* __restrict__ deg, int* __restrict__ out,
                        int* __restrict__ bsum, int N)
{
    __shared__ int sh[256];
    const int t = threadIdx.x;
    const int base = blockIdx.x * SCAN_CHUNK + t * 16;
    int v[16];
    int run = 0;
    #pragma unroll
    for (int i = 0; i < 16; ++i) {
        int idx = base + i;
        v[i] = run;
        run += (idx < N) ? deg[idx] : 0;
    }
    sh[t] = run;
    __syncthreads();
    for (int off = 1; off < 256; off <<= 1) {
        int x = (t >= off) ? sh[t - off] : 0;
        __syncthreads();
        sh[t] += x;
        __syncthreads();
    }
    int texcl = (t == 0) ? 0 : sh[t - 1];
    #pragma unroll
    for (int i = 0; i < 16; ++i) {
        int idx = base + i;
        if (idx < N) out[idx] = texcl + v[i];
    }
    if (t == 255) bsum[blockIdx.x] = sh[255];
}

__global__ void k_scan2(int* bsum, int nb) {
    if (threadIdx.x == 0) {
        int run = 0;
        for (int i = 0; i < nb; ++i) { int v = bsum[i]; bsum[i] = run; run += v; }
    }
}

__global__ void k_scan3(int* __restrict__ cursor, const int* __restrict__ bsum, int N) {
    int off = bsum[blockIdx.x];
    int base = blockIdx.x * SCAN_CHUNK + threadIdx.x;
    #pragma unroll
    for (int i = 0; i < 16; ++i) {
        int idx = base + i * 256;
        if (idx < N) cursor[idx] += off;
    }
}

__global__ void k_scatter(const int* __restrict__ ei, int* __restrict__ cursor,
                          int* __restrict__ csr_src, int E)
{
    int e = blockIdx.x * 256 + threadIdx.x;
    if (e >= E) return;
    int s = ei[e], d = ei[E + e];
    int pos = atomicAdd(&cursor[d], 1);
    csr_src[pos] = s;
}

// ---------- per-dst aggregation: softmax-weighted sum, + conv_b, BN partials ----------
// one wave per node; after scatter, cursor[n] = row end, start = end - deg[n]
__global__ void k_aggregate(const int* __restrict__ csr_src, const int* __restrict__ cursor,
                            const int* __restrict__ deg, const float* __restrict__ aS,
                            const float* __restrict__ aD, const float* __restrict__ h,
                            const float* __restrict__ conv_b, float* __restrict__ hgat,
                            float* __restrict__ bnsum, float* __restrict__ bnsq, int N)
{
    const int t = threadIdx.x;
    const int c = t & 63;
    const int wid = t >> 6;
    const float bc = conv_b[c];
    float psum = 0.f, psq = 0.f;
    const int waveStride = gridDim.x * 4;
    for (int n = blockIdx.x * 4 + wid; n < N; n += waveStride) {
        const int end = cursor[n];
        const int dg = deg[n];
        const int start = end - dg;
        const float aDn = aD[n];
        const float lself = lrelu(aS[n] + aDn);
        // pass 1: segment max (wave-cooperative over edges, chunked by 64)
        float m = lself;
        for (int base = start; base < end; base += 64) {
            int idx = base + c;
            float l = -1e30f;
            if (idx < end) l = lrelu(aS[csr_src[idx]] + aDn);
            #pragma unroll
            for (int off = 32; off; off >>= 1) l = fmaxf(l, __shfl_xor(l, off));
            m = fmaxf(m, l);
        }
        // pass 2: weighted gather-accumulate
        float wsum = __expf(lself - m);
        float acc = wsum * h[(size_t)n * 64 + c];   // self-loop contribution
        for (int base = start; base < end; base += 64) {
            int idx = base + c;
            int   s_l = 0;
            float l_l = -1e30f;
            if (idx < end) { s_l = csr_src[idx]; l_l = lrelu(aS[s_l] + aDn); }
            float w_l = __expf(l_l - m);
            float wsc = w_l;
            #pragma unroll
            for (int off = 32; off; off >>= 1) wsc += __shfl_xor(wsc, off);
            wsum += wsc;
            int cnt = min(64, end - base);
            for (int j = 0; j < cnt; ++j) {
                float w = __shfl(w_l, j);
                int   s = __shfl(s_l, j);
                acc = fmaf(w, h[(size_t)s * 64 + c], acc);
            }
        }
        float v = acc / wsum + bc;
        hgat[(size_t)n * 64 + c] = v;
        psum += v;
        psq = fmaf(v, v, psq);
    }
    __shared__ float ps[4][64], pq[4][64];
    ps[wid][c] = psum;
    pq[wid][c] = psq;
    __syncthreads();
    if (t < 64) {
        float s = ps[0][t] + ps[1][t] + ps[2][t] + ps[3][t];
        float q = pq[0][t] + pq[1][t] + pq[2][t] + pq[3][t];
        unsafeAtomicAdd(&bnsum[t], s);
        unsafeAtomicAdd(&bnsq[t], q);
    }
}

// ---------- BN scale/shift ----------
__global__ void k_bn_params(const float* __restrict__ bnsum, const float* __restrict__ bnsq,
                            const float* __restrict__ gamma, const float* __restrict__ beta,
                            float* __restrict__ scale, float* __restrict__ shift, int N)
{
    int c = threadIdx.x;
    float invN = 1.f / (float)N;
    float mu  = bnsum[c] * invN;
    float var = bnsq[c] * invN - mu * mu;
    float sc  = gamma[c] * rsqrtf(var + BN_EPS);
    scale[c] = sc;
    shift[c] = beta[c] - mu * sc;
}

// ---------- BN apply + ReLU + FC(64->32) ----------
__global__ void k_bn_fc(const float* __restrict__ hg, const float* __restrict__ scale,
                        const float* __restrict__ shift, const float* __restrict__ fcW,
                        const float* __restrict__ fcb, float* __restrict__ out, int N)
{
    __shared__ float Ws[2048];
    __shared__ float sc[64], sh[64];
    const int t = threadIdx.x;
    for (int i = t; i < 2048; i += 256) Ws[i] = fcW[i];
    if (t < 64) { sc[t] = scale[t]; sh[t] = shift[t]; }
    __syncthreads();
    int n = blockIdx.x * 256 + t;
    if (n >= N) return;
    float y[64];
    const float4* hp = (const float4*)(hg + (size_t)n * 64);
    #pragma unroll
    for (int i = 0; i < 16; ++i) {
        float4 v = hp[i];
        y[4*i+0] = fmaxf(fmaf(v.x, sc[4*i+0], sh[4*i+0]), 0.f);
        y[4*i+1] = fmaxf(fmaf(v.y, sc[4*i+1], sh[4*i+1]), 0.f);
        y[4*i+2] = fmaxf(fmaf(v.z, sc[4*i+2], sh[4*i+2]), 0.f);
        y[4*i+3] = fmaxf(fmaf(v.w, sc[4*i+3], sh[4*i+3]), 0.f);
    }
    float4* op = (float4*)(out + (size_t)n * 32);
    #pragma unroll
    for (int o4 = 0; o4 < 8; ++o4) {
        float a0 = fcb[4*o4+0], a1 = fcb[4*o4+1], a2 = fcb[4*o4+2], a3 = fcb[4*o4+3];
        #pragma unroll
        for (int k = 0; k < 64; ++k) {
            float yv = y[k];
            a0 = fmaf(yv, Ws[(4*o4+0)*64+k], a0);
            a1 = fmaf(yv, Ws[(4*o4+1)*64+k], a1);
            a2 = fmaf(yv, Ws[(4*o4+2)*64+k], a2);
            a3 = fmaf(yv, Ws[(4*o4+3)*64+k], a3);
        }
        op[o4] = make_float4(a0, a1, a2, a3);
    }
}

// ---------- launch ----------
extern "C" void kernel_launch(void* const* d_in, const int* in_sizes, int n_in,
                              void* d_out, int out_size, void* d_ws, size_t ws_size,
                              hipStream_t stream)
{
    const float* x       = (const float*)d_in[0];
    const int*   ei      = (const int*)d_in[1];
    const float* W       = (const float*)d_in[2];
    const float* att_src = (const float*)d_in[3];
    const float* att_dst = (const float*)d_in[4];
    const float* conv_b  = (const float*)d_in[5];
    const float* gamma   = (const float*)d_in[6];
    const float* beta    = (const float*)d_in[7];
    const float* fcW     = (const float*)d_in[8];
    const float* fcb     = (const float*)d_in[9];

    const int N = in_sizes[0] / 64;
    const int E = in_sizes[1] / 2;

    // workspace layout
    float* ws = (float*)d_ws;
    size_t N64 = (size_t)N * 64;
    float*    h       = ws;                      // N*64
    float*    hgat    = h + N64;                 // N*64
    float*    aS      = hgat + N64;              // N
    float*    aD      = aS + N;                  // N
    float*    bnsum   = aD + N;                  // 64
    float*    bnsq    = bnsum + 64;              // 64
    float*    scale   = bnsq + 64;               // 64
    float*    shift   = scale + 64;              // 64
    int*      deg     = (int*)(shift + 64);      // N
    int*      cursor  = deg + N;                 // N
    int*      bsum    = cursor + N;              // 256
    int*      csr_src = bsum + 256;              // E

    hipMemsetAsync(deg, 0, (size_t)N * sizeof(int), stream);
    hipMemsetAsync(bnsum, 0, 2 * 64 * sizeof(float), stream);

    k_gemm_h<<<(N + 63) / 64, 256, 0, stream>>>(x, W, att_src, att_dst, h, aS, aD, N);
    k_hist<<<(E + 255) / 256, 256, 0, stream>>>(ei, deg, E);

    int nb = (N + SCAN_CHUNK - 1) / SCAN_CHUNK;
    k_scan1<<<nb, 256, 0, stream>>>(deg, cursor, bsum, N);
    k_scan2<<<1, 64, 0, stream>>>(bsum, nb);
    k_scan3<<<nb, 256, 0, stream>>>(cursor, bsum, N);
    k_scatter<<<(E + 255) / 256, 256, 0, stream>>>(ei, cursor, csr_src, E);

    k_aggregate<<<2048, 256, 0, stream>>>(csr_src, cursor, deg, aS, aD, h, conv_b,
                                          hgat, bnsum, bnsq, N);
    k_bn_params<<<1, 64, 0, stream>>>(bnsum, bnsq, gamma, beta, scale, shift, N);
    k_bn_fc<<<(N + 255) / 256, 256, 0, stream>>>(hgat, scale, shift, fcW, fcb,
                                                 (float*)d_out, N);
}

// Round 6
// 490.446 us; speedup vs baseline: 1.6114x; 1.2077x over previous
//
#include <hip/hip_runtime.h>
#include <hip/hip_bf16.h>

#define NEG_SLOPE 0.2f
#define BN_EPS 1e-5f
#define SCAN_CHUNK 4096

__device__ __forceinline__ float lrelu(float x) { return x > 0.f ? x : NEG_SLOPE * x; }

// ---------- kernel A: h = x@W^T (W rows in regs), aS/aD; fused dst-hist + bn zero ----------
__global__ void __launch_bounds__(256, 4) k_gemm_h(
    const float* __restrict__ x, const float* __restrict__ W,
    const float* __restrict__ att_src, const float* __restrict__ att_dst,
    const int* __restrict__ ei, float* __restrict__ h,
    float* __restrict__ aS, float* __restrict__ aD,
    int* __restrict__ deg, float* __restrict__ bnzero, int N, int E)
{
    __shared__ float4 xs[64][17];   // [node][k4], row = 272B (16B aligned)
    const int t = threadIdx.x;
    const int c = t & 63;
    const int wv = t >> 6;
    const int n0 = blockIdx.x * 64;

    // W row c -> 64 registers (16KB total, L2-resident)
    float Wreg[64];
    const float4* Wp = (const float4*)W;
    #pragma unroll
    for (int k4 = 0; k4 < 16; ++k4) {
        float4 w4 = Wp[c * 16 + k4];
        Wreg[4*k4+0] = w4.x; Wreg[4*k4+1] = w4.y;
        Wreg[4*k4+2] = w4.z; Wreg[4*k4+3] = w4.w;
    }
    // stage x tile (coalesced float4)
    const float4* xp = (const float4*)x;
    #pragma unroll
    for (int i = 0; i < 4; ++i) {
        int idx = i * 256 + t;           // 0..1023
        int row = idx >> 4, k4 = idx & 15;
        xs[row][k4] = (n0 + row < N) ? xp[(size_t)n0 * 16 + idx] : make_float4(0,0,0,0);
    }
    __syncthreads();

    const float asc = att_src[c], adc = att_dst[c];
    for (int i = 0; i < 16; ++i) {
        int nl = wv * 16 + i;
        int n = n0 + nl;
        if (n >= N) break;
        float a = 0.f;
        #pragma unroll
        for (int k4 = 0; k4 < 16; ++k4) {
            float4 xv = xs[nl][k4];      // broadcast b128
            a = fmaf(xv.x, Wreg[4*k4+0], a);
            a = fmaf(xv.y, Wreg[4*k4+1], a);
            a = fmaf(xv.z, Wreg[4*k4+2], a);
            a = fmaf(xv.w, Wreg[4*k4+3], a);
        }
        h[(size_t)n * 64 + c] = a;
        float s = a * asc, d = a * adc;
        #pragma unroll
        for (int off = 32; off; off >>= 1) { s += __shfl_xor(s, off); d += __shfl_xor(d, off); }
        if (c == 0) { aS[n] = s; aD[n] = d; }
    }
    // fused dst histogram
    int per = (E + gridDim.x - 1) / gridDim.x;
    int e0 = blockIdx.x * per;
    int e1 = min(e0 + per, E);
    for (int e = e0 + t; e < e1; e += 256) atomicAdd(&deg[ei[E + e]], 1);
    // zero bn accumulators (used by a LATER kernel; stream order makes this safe)
    if (blockIdx.x == 0 && t < 128) bnzero[t] = 0.f;
}

// ---------- scan (2 kernels; scatter applies block offsets inline) ----------
__global__ void k_scan1(const int* __restrict__ deg, int* __restrict__ out,
                        int* __restrict__ bsum, int N)
{
    __shared__ int sh[256];
    const int t = threadIdx.x;
    const int base = blockIdx.x * SCAN_CHUNK + t * 16;
    int v[16];
    int run = 0;
    #pragma unroll
    for (int i = 0; i < 16; ++i) {
        int idx = base + i;
        v[i] = run;
        run += (idx < N) ? deg[idx] : 0;
    }
    sh[t] = run;
    __syncthreads();
    for (int off = 1; off < 256; off <<= 1) {
        int y = (t >= off) ? sh[t - off] : 0;
        __syncthreads();
        sh[t] += y;
        __syncthreads();
    }
    int texcl = (t == 0) ? 0 : sh[t - 1];
    #pragma unroll
    for (int i = 0; i < 16; ++i) {
        int idx = base + i;
        if (idx < N) out[idx] = texcl + v[i];   // chunk-local exclusive
    }
    if (t == 255) bsum[blockIdx.x] = sh[255];
}

__global__ void k_scan2(int* bsum, int nb)   // nb <= 256
{
    __shared__ int sh[256];
    const int t = threadIdx.x;
    int v = (t < nb) ? bsum[t] : 0;
    sh[t] = v;
    __syncthreads();
    for (int off = 1; off < 256; off <<= 1) {
        int y = (t >= off) ? sh[t - off] : 0;
        __syncthreads();
        sh[t] += y;
        __syncthreads();
    }
    if (t < nb) bsum[t] = sh[t] - v;            // exclusive chunk bases
}

__global__ void k_scatter(const int* __restrict__ ei, int* __restrict__ cursor,
                          const int* __restrict__ bsum, int* __restrict__ csr_src, int E)
{
    int e = blockIdx.x * 256 + threadIdx.x;
    if (e >= E) return;
    int s = ei[e], d = ei[E + e];
    int pos = atomicAdd(&cursor[d], 1) + bsum[d >> 12];
    csr_src[pos] = s;
}

// ---------- per-dst aggregation: 16 lanes/node, float4/lane, shfl-broadcast, no max pass ----------
__global__ void __launch_bounds__(256, 8) k_aggregate(
    const int* __restrict__ csr_src, const int* __restrict__ cursor,
    const int* __restrict__ bsum, const int* __restrict__ deg,
    const float* __restrict__ aS, const float* __restrict__ aD,
    const float* __restrict__ h, const float* __restrict__ conv_b,
    float* __restrict__ hgat, float* __restrict__ bnsum, float* __restrict__ bnsq, int N)
{
    __shared__ float4 ps[256], pq[256];
    const int t = threadIdx.x;
    const int g = t & 15;            // lane in group: channels 4g..4g+3
    const int grp = t >> 4;          // 16 groups per block
    const int lb = (t & 63) & ~15;   // group's base lane within the wave
    const float4* hp = (const float4*)h;
    const float4 bc = ((const float4*)conv_b)[g];
    float4 psum = make_float4(0,0,0,0), psq = make_float4(0,0,0,0);
    const int stride = gridDim.x * 16;

    for (int n = blockIdx.x * 16 + grp; n < N; n += stride) {
        const int dg = deg[n];
        const int end = cursor[n] + bsum[n >> 12];
        const int start = end - dg;
        const float aDn = aD[n];
        const float wself = __expf(lrelu(aS[n] + aDn));
        float4 hs = hp[(size_t)n * 16 + g];
        float4 acc;
        acc.x = wself * hs.x; acc.y = wself * hs.y;
        acc.z = wself * hs.z; acc.w = wself * hs.w;
        float wpart = (g == 0) ? wself : 0.f;

        for (int base = start; base < end; base += 16) {
            int cnt = end - base; cnt = cnt > 16 ? 16 : cnt;
            int   s_l = 0;
            float w_l = 0.f;
            if (g < cnt) {
                s_l = csr_src[base + g];
                w_l = __expf(lrelu(aS[s_l] + aDn));
                wpart += w_l;
                s_l <<= 4;            // float4 base index
            }
            int j = 0;
            for (; j + 4 <= cnt; j += 4) {
                float w0 = __shfl(w_l, lb+j+0); int s0 = __shfl(s_l, lb+j+0);
                float w1 = __shfl(w_l, lb+j+1); int s1 = __shfl(s_l, lb+j+1);
                float w2 = __shfl(w_l, lb+j+2); int s2 = __shfl(s_l, lb+j+2);
                float w3 = __shfl(w_l, lb+j+3); int s3 = __shfl(s_l, lb+j+3);
                float4 h0 = hp[s0 + g];
                float4 h1 = hp[s1 + g];
                float4 h2 = hp[s2 + g];
                float4 h3 = hp[s3 + g];
                acc.x = fmaf(w0,h0.x,acc.x); acc.y = fmaf(w0,h0.y,acc.y);
                acc.z = fmaf(w0,h0.z,acc.z); acc.w = fmaf(w0,h0.w,acc.w);
                acc.x = fmaf(w1,h1.x,acc.x); acc.y = fmaf(w1,h1.y,acc.y);
                acc.z = fmaf(w1,h1.z,acc.z); acc.w = fmaf(w1,h1.w,acc.w);
                acc.x = fmaf(w2,h2.x,acc.x); acc.y = fmaf(w2,h2.y,acc.y);
                acc.z = fmaf(w2,h2.z,acc.z); acc.w = fmaf(w2,h2.w,acc.w);
                acc.x = fmaf(w3,h3.x,acc.x); acc.y = fmaf(w3,h3.y,acc.y);
                acc.z = fmaf(w3,h3.z,acc.z); acc.w = fmaf(w3,h3.w,acc.w);
            }
            for (; j < cnt; ++j) {
                float w0 = __shfl(w_l, lb+j); int s0 = __shfl(s_l, lb+j);
                float4 h0 = hp[s0 + g];
                acc.x = fmaf(w0,h0.x,acc.x); acc.y = fmaf(w0,h0.y,acc.y);
                acc.z = fmaf(w0,h0.z,acc.z); acc.w = fmaf(w0,h0.w,acc.w);
            }
        }
        #pragma unroll
        for (int off = 8; off; off >>= 1) wpart += __shfl_xor(wpart, off);
        float inv = 1.f / wpart;
        float4 v;
        v.x = fmaf(acc.x, inv, bc.x); v.y = fmaf(acc.y, inv, bc.y);
        v.z = fmaf(acc.z, inv, bc.z); v.w = fmaf(acc.w, inv, bc.w);
        ((float4*)hgat)[(size_t)n * 16 + g] = v;
        psum.x += v.x; psum.y += v.y; psum.z += v.z; psum.w += v.w;
        psq.x = fmaf(v.x,v.x,psq.x); psq.y = fmaf(v.y,v.y,psq.y);
        psq.z = fmaf(v.z,v.z,psq.z); psq.w = fmaf(v.w,v.w,psq.w);
    }
    ps[t] = psum; pq[t] = psq;
    __syncthreads();
    if (t < 64) {
        int gg = t >> 2, comp = t & 3;
        float s = 0.f, q = 0.f;
        #pragma unroll
        for (int k = 0; k < 16; ++k) {
            const float* pp = (const float*)&ps[k * 16 + gg];
            const float* qq = (const float*)&pq[k * 16 + gg];
            s += pp[comp]; q += qq[comp];
        }
        unsafeAtomicAdd(&bnsum[t], s);
        unsafeAtomicAdd(&bnsq[t], q);
    }
}

// ---------- BN params (per-block) + BN apply + ReLU + FC(64->32) ----------
__global__ void k_bn_fc(const float* __restrict__ hg, const float* __restrict__ bnsum,
                        const float* __restrict__ bnsq, const float* __restrict__ gamma,
                        const float* __restrict__ beta, const float* __restrict__ fcW,
                        const float* __restrict__ fcb, float* __restrict__ out, int N)
{
    __shared__ float Ws[2048];
    __shared__ float sc[64], sh[64];
    const int t = threadIdx.x;
    for (int i = t; i < 2048; i += 256) Ws[i] = fcW[i];
    if (t < 64) {
        float invN = 1.f / (float)N;
        float mu  = bnsum[t] * invN;
        float var = bnsq[t] * invN - mu * mu;
        float s   = gamma[t] * rsqrtf(var + BN_EPS);
        sc[t] = s;
        sh[t] = beta[t] - mu * s;
    }
    __syncthreads();
    int n = blockIdx.x * 256 + t;
    if (n >= N) return;
    float y[64];
    const float4* hp = (const float4*)(hg + (size_t)n * 64);
    #pragma unroll
    for (int i = 0; i < 16; ++i) {
        float4 v = hp[i];
        y[4*i+0] = fmaxf(fmaf(v.x, sc[4*i+0], sh[4*i+0]), 0.f);
        y[4*i+1] = fmaxf(fmaf(v.y, sc[4*i+1], sh[4*i+1]), 0.f);
        y[4*i+2] = fmaxf(fmaf(v.z, sc[4*i+2], sh[4*i+2]), 0.f);
        y[4*i+3] = fmaxf(fmaf(v.w, sc[4*i+3], sh[4*i+3]), 0.f);
    }
    float4* op = (float4*)(out + (size_t)n * 32);
    #pragma unroll
    for (int o4 = 0; o4 < 8; ++o4) {
        float a0 = fcb[4*o4+0], a1 = fcb[4*o4+1], a2 = fcb[4*o4+2], a3 = fcb[4*o4+3];
        #pragma unroll
        for (int k = 0; k < 64; ++k) {
            float yv = y[k];
            a0 = fmaf(yv, Ws[(4*o4+0)*64+k], a0);
            a1 = fmaf(yv, Ws[(4*o4+1)*64+k], a1);
            a2 = fmaf(yv, Ws[(4*o4+2)*64+k], a2);
            a3 = fmaf(yv, Ws[(4*o4+3)*64+k], a3);
        }
        op[o4] = make_float4(a0, a1, a2, a3);
    }
}

// ---------- launch ----------
extern "C" void kernel_launch(void* const* d_in, const int* in_sizes, int n_in,
                              void* d_out, int out_size, void* d_ws, size_t ws_size,
                              hipStream_t stream)
{
    const float* x       = (const float*)d_in[0];
    const int*   ei      = (const int*)d_in[1];
    const float* W       = (const float*)d_in[2];
    const float* att_src = (const float*)d_in[3];
    const float* att_dst = (const float*)d_in[4];
    const float* conv_b  = (const float*)d_in[5];
    const float* gamma   = (const float*)d_in[6];
    const float* beta    = (const float*)d_in[7];
    const float* fcW     = (const float*)d_in[8];
    const float* fcb     = (const float*)d_in[9];

    const int N = in_sizes[0] / 64;
    const int E = in_sizes[1] / 2;

    // workspace layout
    float* ws = (float*)d_ws;
    size_t N64 = (size_t)N * 64;
    float*    h       = ws;                      // N*64
    float*    hgat    = h + N64;                 // N*64
    float*    aS      = hgat + N64;              // N
    float*    aD      = aS + N;                  // N
    float*    bnsum   = aD + N;                  // 64
    float*    bnsq    = bnsum + 64;              // 64
    int*      deg     = (int*)(bnsq + 64);       // N
    int*      cursor  = deg + N;                 // N
    int*      bsum    = cursor + N;              // 256
    int*      csr_src = bsum + 256;              // E

    hipMemsetAsync(deg, 0, (size_t)N * sizeof(int), stream);

    k_gemm_h<<<(N + 63) / 64, 256, 0, stream>>>(x, W, att_src, att_dst, ei,
                                                h, aS, aD, deg, bnsum, N, E);
    int nb = (N + SCAN_CHUNK - 1) / SCAN_CHUNK;
    k_scan1<<<nb, 256, 0, stream>>>(deg, cursor, bsum, N);
    k_scan2<<<1, 256, 0, stream>>>(bsum, nb);
    k_scatter<<<(E + 255) / 256, 256, 0, stream>>>(ei, cursor, bsum, csr_src, E);

    k_aggregate<<<2048, 256, 0, stream>>>(csr_src, cursor, bsum, deg, aS, aD, h,
                                          conv_b, hgat, bnsum, bnsq, N);
    k_bn_fc<<<(N + 255) / 256, 256, 0, stream>>>(hgat, bnsum, bnsq, gamma, beta,
                                                 fcW, fcb, (float*)d_out, N);
}